// Round 1
// baseline (983.009 us; speedup 1.0000x reference)
//
#include <hip/hip_runtime.h>

// ---------------------------------------------------------------------------
// GAT edge classifier, MI355X. Structure:
//   CSR build (deg hist -> scan -> scatter)            [int atomics only]
//   GEMM1 xp = x @ W1                                  [fp32 vector]
//   attn node dots a_src1/a_dst1
//   agg1: per-dst softmax-aggregate (2 passes, no atomics) -> h1 (relu+bias)
//   GEMM2 xp2 = h1 @ W2
//   attn node dots a_src2/a_dst2
//   agg2: per-dst aggregate + fused uv = h2 @ [WcTop|WcBot] via shfl reduce
//   classify: out[e] = u[row] + v[col] + bc
// ---------------------------------------------------------------------------

#define NEG 0.2f

__global__ __launch_bounds__(256) void k_init(int* deg, int* cur, int n) {
    int i = blockIdx.x * 256 + threadIdx.x;
    if (i < n) { deg[i] = 1; cur[i] = 0; }  // deg starts at 1 for self-loop
}

__global__ __launch_bounds__(256) void k_hist(const int* __restrict__ ei, int* deg, int E) {
    int e = blockIdx.x * 256 + threadIdx.x;
    if (e < E) atomicAdd(&deg[ei[E + e]], 1);   // dst = ei[1][e]
}

__global__ __launch_bounds__(1024) void k_scan(const int* __restrict__ deg, int* __restrict__ rowptr, int n) {
    __shared__ int sums[1024];
    int t = threadIdx.x;
    int chunk = (n + 1023) >> 10;
    int lo = t * chunk, hi = min(lo + chunk, n);
    int s = 0;
    for (int i = lo; i < hi; i++) s += deg[i];
    sums[t] = s;
    __syncthreads();
    for (int off = 1; off < 1024; off <<= 1) {
        int v = (t >= off) ? sums[t - off] : 0;
        __syncthreads();
        sums[t] += v;
        __syncthreads();
    }
    int run = sums[t] - s;  // exclusive prefix at lo
    for (int i = lo; i < hi; i++) { rowptr[i] = run; run += deg[i]; }
    if (t == 1023) rowptr[n] = sums[1023];
}

__global__ __launch_bounds__(256) void k_scatter(const int* __restrict__ ei, const int* __restrict__ rowptr,
                                                 int* cur, int* csr_src, int E, int N) {
    int e = blockIdx.x * 256 + threadIdx.x;
    if (e < E) {
        int d = ei[E + e];
        int pos = rowptr[d] + atomicAdd(&cur[d], 1);
        csr_src[pos] = ei[e];
    } else if (e < E + N) {
        int i = e - E;  // self loop
        int pos = rowptr[i] + atomicAdd(&cur[i], 1);
        csr_src[pos] = i;
    }
}

// xp[M,256] = x[M,256] @ W[256,256]. Block: 256 thr (one per out col), 32 rows.
__global__ __launch_bounds__(256) void k_gemm1(const float* __restrict__ x, const float* __restrict__ W,
                                               float* __restrict__ xp, int M) {
    __shared__ float xs[32][65];
    int c = threadIdx.x;
    int m0 = blockIdx.x * 32;
    float acc[32];
#pragma unroll
    for (int i = 0; i < 32; i++) acc[i] = 0.f;
    for (int k0 = 0; k0 < 256; k0 += 64) {
        __syncthreads();
        for (int i = threadIdx.x; i < 32 * 64; i += 256) {
            int mm = i >> 6, kk = i & 63;
            int m = m0 + mm;
            xs[mm][kk] = (m < M) ? x[(size_t)m * 256 + k0 + kk] : 0.f;
        }
        __syncthreads();
#pragma unroll 4
        for (int kk = 0; kk < 64; kk++) {
            float w = W[(k0 + kk) * 256 + c];
#pragma unroll
            for (int mm = 0; mm < 32; mm++) acc[mm] += xs[mm][kk] * w;
        }
    }
    for (int mm = 0; mm < 32; mm++) {
        int m = m0 + mm;
        if (m < M) xp[(size_t)m * 256 + c] = acc[mm];
    }
}

// a_src1/a_dst1[n,h] = sum_c xp[n,h,c]*att[h,c]
__global__ __launch_bounds__(256) void k_attn1(const float* __restrict__ xp, const float* __restrict__ att_s,
                                               const float* __restrict__ att_d, float* __restrict__ as,
                                               float* __restrict__ ad, int M) {
    int idx = blockIdx.x * 256 + threadIdx.x;
    if (idx >= M * 4) return;
    int n = idx >> 2, h = idx & 3;
    const float* row = xp + (size_t)n * 256 + h * 64;
    float s = 0.f, d = 0.f;
#pragma unroll 8
    for (int c = 0; c < 64; c++) { float v = row[c]; s += v * att_s[h * 64 + c]; d += v * att_d[h * 64 + c]; }
    as[idx] = s; ad[idx] = d;
}

// per-dst-node softmax aggregate, layer 1. block = 256 thr (t = h*64+c), 1 node/block
__global__ __launch_bounds__(256) void k_agg1(const float* __restrict__ xp, const float* __restrict__ as,
                                              const float* __restrict__ ad, const int* __restrict__ rowptr,
                                              const int* __restrict__ csr_src, const float* __restrict__ b1,
                                              float* __restrict__ h1, int M) {
    int n = blockIdx.x;
    int t = threadIdx.x;
    int h = t >> 6;
    int start = rowptr[n], end = rowptr[n + 1];
    float adv = ad[n * 4 + h];
    float amax = -1e30f;
    for (int e = start; e < end; e++) {
        int s = csr_src[e];
        float raw = as[s * 4 + h] + adv;
        raw = raw > 0.f ? raw : NEG * raw;
        amax = fmaxf(amax, raw);
    }
    float den = 0.f, acc = 0.f;
    for (int e = start; e < end; e++) {
        int s = csr_src[e];
        float raw = as[s * 4 + h] + adv;
        raw = raw > 0.f ? raw : NEG * raw;
        float p = __expf(raw - amax);
        den += p;
        acc += p * xp[(size_t)s * 256 + t];
    }
    float o = acc / (den + 1e-16f) + b1[t];
    h1[(size_t)n * 256 + t] = fmaxf(o, 0.f);   // relu between layers
}

// xp2[M,64] = h1[M,256] @ W2[256,64]. Block 256 thr: c=t&63, g=t>>6 owns 16 rows.
__global__ __launch_bounds__(256) void k_gemm2(const float* __restrict__ h1, const float* __restrict__ W2,
                                               float* __restrict__ xp2, int M) {
    __shared__ float hs[64][65];
    int t = threadIdx.x;
    int c = t & 63, g = t >> 6;
    int m0 = blockIdx.x * 64;
    float acc[16];
#pragma unroll
    for (int i = 0; i < 16; i++) acc[i] = 0.f;
    for (int k0 = 0; k0 < 256; k0 += 64) {
        __syncthreads();
        for (int i = t; i < 64 * 64; i += 256) {
            int mm = i >> 6, kk = i & 63;
            int m = m0 + mm;
            hs[mm][kk] = (m < M) ? h1[(size_t)m * 256 + k0 + kk] : 0.f;
        }
        __syncthreads();
#pragma unroll 4
        for (int kk = 0; kk < 64; kk++) {
            float w = W2[(k0 + kk) * 64 + c];
#pragma unroll
            for (int i = 0; i < 16; i++) acc[i] += hs[g * 16 + i][kk] * w;
        }
    }
    for (int i = 0; i < 16; i++) {
        int m = m0 + g * 16 + i;
        if (m < M) xp2[(size_t)m * 64 + c] = acc[i];
    }
}

__global__ __launch_bounds__(256) void k_attn2(const float* __restrict__ xp2, const float* __restrict__ att_s,
                                               const float* __restrict__ att_d, float* __restrict__ as,
                                               float* __restrict__ ad, int M) {
    int n = blockIdx.x * 256 + threadIdx.x;
    if (n >= M) return;
    const float* row = xp2 + (size_t)n * 64;
    float s = 0.f, d = 0.f;
#pragma unroll 8
    for (int c = 0; c < 64; c++) { float v = row[c]; s += v * att_s[c]; d += v * att_d[c]; }
    as[n] = s; ad[n] = d;
}

// layer-2 aggregate, 1 head, C=64. One wave per node; fused uv = h2 . Wc halves.
__global__ __launch_bounds__(256) void k_agg2(const float* __restrict__ xp2, const float* __restrict__ as,
                                              const float* __restrict__ ad, const int* __restrict__ rowptr,
                                              const int* __restrict__ csr_src, const float* __restrict__ b2,
                                              const float* __restrict__ Wc, float* __restrict__ h2,
                                              float* __restrict__ uv, int M) {
    int wave = threadIdx.x >> 6, lane = threadIdx.x & 63;
    int n = blockIdx.x * 4 + wave;
    if (n >= M) return;
    int start = rowptr[n], end = rowptr[n + 1];
    float adv = ad[n];
    float amax = -1e30f;
    for (int e = start; e < end; e++) {
        float raw = as[csr_src[e]] + adv;
        raw = raw > 0.f ? raw : NEG * raw;
        amax = fmaxf(amax, raw);
    }
    float den = 0.f, acc = 0.f;
    for (int e = start; e < end; e++) {
        int s = csr_src[e];
        float raw = as[s] + adv;
        raw = raw > 0.f ? raw : NEG * raw;
        float p = __expf(raw - amax);
        den += p;
        acc += p * xp2[(size_t)s * 64 + lane];
    }
    float val = acc / (den + 1e-16f) + b2[lane];
    h2[(size_t)n * 64 + lane] = val;
    // uv[j] = sum_l val_l * Wc[l][j] (u), Wc[64+l][j] (v);  Wc is [128,4]
    float pr[8];
#pragma unroll
    for (int j = 0; j < 4; j++) {
        pr[j]     = val * Wc[lane * 4 + j];
        pr[4 + j] = val * Wc[(64 + lane) * 4 + j];
    }
#pragma unroll
    for (int off = 32; off; off >>= 1)
#pragma unroll
        for (int j = 0; j < 8; j++) pr[j] += __shfl_xor(pr[j], off, 64);
    if (lane == 0) {
        float4* o = (float4*)(uv + (size_t)n * 8);
        o[0] = make_float4(pr[0], pr[1], pr[2], pr[3]);
        o[1] = make_float4(pr[4], pr[5], pr[6], pr[7]);
    }
}

__global__ __launch_bounds__(256) void k_classify(const int* __restrict__ ei, const float* __restrict__ uv,
                                                  const float* __restrict__ bc, float* __restrict__ out, int E) {
    int e = blockIdx.x * 256 + threadIdx.x;
    if (e >= E) return;
    int r = ei[e];
    int c = ei[E + e];
    float4 u = *(const float4*)(uv + (size_t)r * 8);
    float4 v = *(const float4*)(uv + (size_t)c * 8 + 4);
    float4 o;
    o.x = u.x + v.x + bc[0];
    o.y = u.y + v.y + bc[1];
    o.z = u.z + v.z + bc[2];
    o.w = u.w + v.w + bc[3];
    *(float4*)(out + (size_t)e * 4) = o;
}

extern "C" void kernel_launch(void* const* d_in, const int* in_sizes, int n_in,
                              void* d_out, int out_size, void* d_ws, size_t ws_size,
                              hipStream_t stream) {
    const float* x    = (const float*)d_in[0];
    const int*   ei   = (const int*)d_in[1];
    // d_in[2] = w (edge weights) is ignored by the reference
    const float* W1   = (const float*)d_in[3];
    const float* atS1 = (const float*)d_in[4];
    const float* atD1 = (const float*)d_in[5];
    const float* b1   = (const float*)d_in[6];
    const float* W2   = (const float*)d_in[7];
    const float* atS2 = (const float*)d_in[8];
    const float* atD2 = (const float*)d_in[9];
    const float* b2   = (const float*)d_in[10];
    const float* Wc   = (const float*)d_in[11];
    const float* bc   = (const float*)d_in[12];
    float* out = (float*)d_out;

    const int N = in_sizes[0] / 256;
    const int E = in_sizes[1] / 2;
    const int Etot = E + N;

    char* w = (char*)d_ws;
    size_t off = 0;
    auto alloc = [&](size_t b) { size_t o = off; off = (o + b + 255) & ~(size_t)255; return o; };
    size_t oA   = alloc((size_t)N * 256 * 4);  // xp; later sub-divided: xp2 | h2 | uv
    size_t oH1  = alloc((size_t)N * 256 * 4);
    size_t oAS1 = alloc((size_t)N * 4 * 4);
    size_t oAD1 = alloc((size_t)N * 4 * 4);
    size_t oAS2 = alloc((size_t)N * 4);
    size_t oAD2 = alloc((size_t)N * 4);
    size_t oDEG = alloc((size_t)N * 4);
    size_t oCUR = alloc((size_t)N * 4);
    size_t oRP  = alloc((size_t)(N + 1) * 4);
    size_t oCSR = alloc((size_t)Etot * 4);
    (void)ws_size;

    float* xp  = (float*)(w + oA);
    float* h1  = (float*)(w + oH1);
    float* xp2 = (float*)(w + oA);                           // alias (xp dead after agg1)
    float* h2  = (float*)(w + oA + (size_t)N * 64 * 4);
    float* uv  = (float*)(w + oA + (size_t)N * 128 * 4);
    float* as1 = (float*)(w + oAS1);
    float* ad1 = (float*)(w + oAD1);
    float* as2 = (float*)(w + oAS2);
    float* ad2 = (float*)(w + oAD2);
    int* deg    = (int*)(w + oDEG);
    int* cur    = (int*)(w + oCUR);
    int* rowptr = (int*)(w + oRP);
    int* csr    = (int*)(w + oCSR);

    // CSR build
    k_init<<<(N + 255) / 256, 256, 0, stream>>>(deg, cur, N);
    k_hist<<<(E + 255) / 256, 256, 0, stream>>>(ei, deg, E);
    k_scan<<<1, 1024, 0, stream>>>(deg, rowptr, N);
    k_scatter<<<(Etot + 255) / 256, 256, 0, stream>>>(ei, rowptr, cur, csr, E, N);

    // Layer 1
    k_gemm1<<<(N + 31) / 32, 256, 0, stream>>>(x, W1, xp, N);
    k_attn1<<<(N * 4 + 255) / 256, 256, 0, stream>>>(xp, atS1, atD1, as1, ad1, N);
    k_agg1<<<N, 256, 0, stream>>>(xp, as1, ad1, rowptr, csr, b1, h1, N);

    // Layer 2
    k_gemm2<<<(N + 63) / 64, 256, 0, stream>>>(h1, W2, xp2, N);
    k_attn2<<<(N + 255) / 256, 256, 0, stream>>>(xp2, atS2, atD2, as2, ad2, N);
    k_agg2<<<(N + 3) / 4, 256, 0, stream>>>(xp2, as2, ad2, rowptr, csr, b2, Wc, h2, uv, N);

    // Edge classifier
    k_classify<<<(E + 255) / 256, 256, 0, stream>>>(ei, uv, bc, out, E);
}

// Round 2
// 787.543 us; speedup vs baseline: 1.2482x; 1.2482x over previous
//
#include <hip/hip_runtime.h>

// ---------------------------------------------------------------------------
// GAT edge classifier, MI355X.
//   CSR build (deg hist -> scan -> scatter)            [int atomics only]
//   pack: x -> (xh, xl) bf16 split; W1,W2 -> transposed bf16 splits
//   GEMM1 xp = x @ W1 via MFMA 16x16x32 bf16, 3-term split (hh + hl + lh)
//   attn node dots a_src1/a_dst1
//   agg1: per-dst softmax-aggregate -> h1 written as bf16 split (relu+bias)
//   GEMM2 xp2 = h1 @ W2 via same MFMA kernel
//   attn node dots a_src2/a_dst2
//   agg2: per-dst aggregate + fused uv = h2 @ [WcTop|WcBot] via shfl reduce
//   classify: out[e] = u[row] + v[col] + bc
// ---------------------------------------------------------------------------

#define NEG 0.2f

typedef __attribute__((ext_vector_type(8))) short bf16x8;
typedef __attribute__((ext_vector_type(4))) float f32x4;

__device__ __forceinline__ unsigned short f2bf(float f) {
    unsigned int u = __float_as_uint(f);
    unsigned int r = (u + 0x7FFFu + ((u >> 16) & 1u)) >> 16;   // round-nearest-even
    return (unsigned short)r;
}
__device__ __forceinline__ float bf2f(unsigned short h) {
    return __uint_as_float(((unsigned int)h) << 16);
}

// ------------------------------- CSR build --------------------------------

__global__ __launch_bounds__(256) void k_init(int* deg, int* cur, int n) {
    int i = blockIdx.x * 256 + threadIdx.x;
    if (i < n) { deg[i] = 1; cur[i] = 0; }  // deg starts at 1 for self-loop
}

__global__ __launch_bounds__(256) void k_hist(const int* __restrict__ ei, int* deg, int E) {
    int e = blockIdx.x * 256 + threadIdx.x;
    if (e < E) atomicAdd(&deg[ei[E + e]], 1);   // dst = ei[1][e]
}

__global__ __launch_bounds__(1024) void k_scan(const int* __restrict__ deg, int* __restrict__ rowptr, int n) {
    __shared__ int sums[1024];
    int t = threadIdx.x;
    int chunk = (n + 1023) >> 10;
    int lo = t * chunk, hi = min(lo + chunk, n);
    int s = 0;
    for (int i = lo; i < hi; i++) s += deg[i];
    sums[t] = s;
    __syncthreads();
    for (int off = 1; off < 1024; off <<= 1) {
        int v = (t >= off) ? sums[t - off] : 0;
        __syncthreads();
        sums[t] += v;
        __syncthreads();
    }
    int run = sums[t] - s;  // exclusive prefix at lo
    for (int i = lo; i < hi; i++) { rowptr[i] = run; run += deg[i]; }
    if (t == 1023) rowptr[n] = sums[1023];
}

__global__ __launch_bounds__(256) void k_scatter(const int* __restrict__ ei, const int* __restrict__ rowptr,
                                                 int* cur, int* csr_src, int E, int N) {
    int e = blockIdx.x * 256 + threadIdx.x;
    if (e < E) {
        int d = ei[E + e];
        int pos = rowptr[d] + atomicAdd(&cur[d], 1);
        csr_src[pos] = ei[e];
    } else if (e < E + N) {
        int i = e - E;  // self loop
        int pos = rowptr[i] + atomicAdd(&cur[i], 1);
        csr_src[pos] = i;
    }
}

// ------------------------------- packing ----------------------------------

// split fp32 -> bf16 hi + bf16 lo (residual), elementwise, vectorized
__global__ __launch_bounds__(256) void k_pack_split(const float* __restrict__ src,
                                                    unsigned short* __restrict__ hi,
                                                    unsigned short* __restrict__ lo, long n4) {
    long i = (long)blockIdx.x * 256 + threadIdx.x;
    long stride = (long)gridDim.x * 256;
    for (; i < n4; i += stride) {
        float4 v = ((const float4*)src)[i];
        unsigned short h0 = f2bf(v.x), h1 = f2bf(v.y), h2 = f2bf(v.z), h3 = f2bf(v.w);
        ushort4 H = make_ushort4(h0, h1, h2, h3);
        ushort4 L = make_ushort4(f2bf(v.x - bf2f(h0)), f2bf(v.y - bf2f(h1)),
                                 f2bf(v.z - bf2f(h2)), f2bf(v.w - bf2f(h3)));
        ((ushort4*)hi)[i] = H;
        ((ushort4*)lo)[i] = L;
    }
}

// W [K,N] fp32 -> WT hi/lo bf16 [N,K]
__global__ __launch_bounds__(256) void k_pack_wT(const float* __restrict__ W,
                                                 unsigned short* __restrict__ hiT,
                                                 unsigned short* __restrict__ loT, int K, int N) {
    int t = blockIdx.x * 256 + threadIdx.x;
    if (t >= K * N) return;
    int n = t / K, k = t - n * K;
    float v = W[(size_t)k * N + n];
    unsigned short h = f2bf(v);
    hiT[t] = h;
    loT[t] = f2bf(v - bf2f(h));
}

// ------------------------------- MFMA GEMM --------------------------------
// C[M,N] = A[M,K] @ B[K,N], A given as hi/lo bf16 row-major, B as hi/lo bf16
// TRANSPOSED [N,K]. 3-term split product. Block: 256 thr = 4 waves, block
// tile 64 rows x 64 cols, wave tile 16 x 64 (4 n-frags).
// frag layout (16x16x32): A: row=lane&15, k=(lane>>4)*8+j ; B: col=lane&15,
// k=(lane>>4)*8+j (read from B^T row) ; C/D: col=lane&15, row=(lane>>4)*4+reg.
__global__ __launch_bounds__(256) void k_mfma_gemm(const unsigned short* __restrict__ Ah,
                                                   const unsigned short* __restrict__ Al,
                                                   const unsigned short* __restrict__ BhT,
                                                   const unsigned short* __restrict__ BlT,
                                                   float* __restrict__ C, int M, int N, int K) {
    int wv = threadIdx.x >> 6, l = threadIdx.x & 63;
    int r = l & 15, hk = l >> 4;
    int m0 = blockIdx.x * 64 + wv * 16;
    int n0 = blockIdx.y * 64;
    int arow = min(m0 + r, M - 1);
    const unsigned short* aph = Ah + (size_t)arow * K + hk * 8;
    const unsigned short* apl = Al + (size_t)arow * K + hk * 8;
    const unsigned short* bbase = BhT + (size_t)(n0 + r) * K + hk * 8;
    const unsigned short* bbasel = BlT + (size_t)(n0 + r) * K + hk * 8;

    f32x4 acc[4] = {f32x4{0,0,0,0}, f32x4{0,0,0,0}, f32x4{0,0,0,0}, f32x4{0,0,0,0}};

#pragma unroll 2
    for (int k0 = 0; k0 < K; k0 += 32) {
        bf16x8 ah = *(const bf16x8*)(aph + k0);
        bf16x8 al = *(const bf16x8*)(apl + k0);
#pragma unroll
        for (int nf = 0; nf < 4; nf++) {
            bf16x8 bh = *(const bf16x8*)(bbase + (size_t)nf * 16 * K + k0);
            bf16x8 bl = *(const bf16x8*)(bbasel + (size_t)nf * 16 * K + k0);
            acc[nf] = __builtin_amdgcn_mfma_f32_16x16x32_bf16(ah, bh, acc[nf], 0, 0, 0);
            acc[nf] = __builtin_amdgcn_mfma_f32_16x16x32_bf16(ah, bl, acc[nf], 0, 0, 0);
            acc[nf] = __builtin_amdgcn_mfma_f32_16x16x32_bf16(al, bh, acc[nf], 0, 0, 0);
        }
    }
#pragma unroll
    for (int nf = 0; nf < 4; nf++) {
#pragma unroll
        for (int j = 0; j < 4; j++) {
            int m = m0 + hk * 4 + j;
            if (m < M) C[(size_t)m * N + n0 + nf * 16 + r] = acc[nf][j];
        }
    }
}

// ------------------------------- attention --------------------------------

__global__ __launch_bounds__(256) void k_attn1(const float* __restrict__ xp, const float* __restrict__ att_s,
                                               const float* __restrict__ att_d, float* __restrict__ as,
                                               float* __restrict__ ad, int M) {
    int idx = blockIdx.x * 256 + threadIdx.x;
    if (idx >= M * 4) return;
    int n = idx >> 2, h = idx & 3;
    const float* row = xp + (size_t)n * 256 + h * 64;
    float s = 0.f, d = 0.f;
#pragma unroll 8
    for (int c = 0; c < 64; c++) { float v = row[c]; s += v * att_s[h * 64 + c]; d += v * att_d[h * 64 + c]; }
    as[idx] = s; ad[idx] = d;
}

// per-dst-node softmax aggregate, layer 1. Writes h1 as bf16 split (relu'd).
__global__ __launch_bounds__(256) void k_agg1(const float* __restrict__ xp, const float* __restrict__ as,
                                              const float* __restrict__ ad, const int* __restrict__ rowptr,
                                              const int* __restrict__ csr_src, const float* __restrict__ b1,
                                              unsigned short* __restrict__ h1h, unsigned short* __restrict__ h1l,
                                              int M) {
    int n = blockIdx.x;
    int t = threadIdx.x;
    int h = t >> 6;
    int start = rowptr[n], end = rowptr[n + 1];
    float adv = ad[n * 4 + h];
    float amax = -1e30f;
    for (int e = start; e < end; e++) {
        int s = csr_src[e];
        float raw = as[s * 4 + h] + adv;
        raw = raw > 0.f ? raw : NEG * raw;
        amax = fmaxf(amax, raw);
    }
    float den = 0.f, acc = 0.f;
    for (int e = start; e < end; e++) {
        int s = csr_src[e];
        float raw = as[s * 4 + h] + adv;
        raw = raw > 0.f ? raw : NEG * raw;
        float p = __expf(raw - amax);
        den += p;
        acc += p * xp[(size_t)s * 256 + t];
    }
    float o = fmaxf(acc / (den + 1e-16f) + b1[t], 0.f);
    unsigned short hh = f2bf(o);
    h1h[(size_t)n * 256 + t] = hh;
    h1l[(size_t)n * 256 + t] = f2bf(o - bf2f(hh));
}

__global__ __launch_bounds__(256) void k_attn2(const float* __restrict__ xp2, const float* __restrict__ att_s,
                                               const float* __restrict__ att_d, float* __restrict__ as,
                                               float* __restrict__ ad, int M) {
    int n = blockIdx.x * 256 + threadIdx.x;
    if (n >= M) return;
    const float* row = xp2 + (size_t)n * 64;
    float s = 0.f, d = 0.f;
#pragma unroll 8
    for (int c = 0; c < 64; c++) { float v = row[c]; s += v * att_s[c]; d += v * att_d[c]; }
    as[n] = s; ad[n] = d;
}

// layer-2 aggregate, 1 head, C=64. One wave per node; fused uv = h2 . Wc halves.
__global__ __launch_bounds__(256) void k_agg2(const float* __restrict__ xp2, const float* __restrict__ as,
                                              const float* __restrict__ ad, const int* __restrict__ rowptr,
                                              const int* __restrict__ csr_src, const float* __restrict__ b2,
                                              const float* __restrict__ Wc, float* __restrict__ h2,
                                              float* __restrict__ uv, int M) {
    int wave = threadIdx.x >> 6, lane = threadIdx.x & 63;
    int n = blockIdx.x * 4 + wave;
    if (n >= M) return;
    int start = rowptr[n], end = rowptr[n + 1];
    float adv = ad[n];
    float amax = -1e30f;
    for (int e = start; e < end; e++) {
        float raw = as[csr_src[e]] + adv;
        raw = raw > 0.f ? raw : NEG * raw;
        amax = fmaxf(amax, raw);
    }
    float den = 0.f, acc = 0.f;
    for (int e = start; e < end; e++) {
        int s = csr_src[e];
        float raw = as[s] + adv;
        raw = raw > 0.f ? raw : NEG * raw;
        float p = __expf(raw - amax);
        den += p;
        acc += p * xp2[(size_t)s * 64 + lane];
    }
    float val = acc / (den + 1e-16f) + b2[lane];
    h2[(size_t)n * 64 + lane] = val;
    float pr[8];
#pragma unroll
    for (int j = 0; j < 4; j++) {
        pr[j]     = val * Wc[lane * 4 + j];
        pr[4 + j] = val * Wc[(64 + lane) * 4 + j];
    }
#pragma unroll
    for (int off = 32; off; off >>= 1)
#pragma unroll
        for (int j = 0; j < 8; j++) pr[j] += __shfl_xor(pr[j], off, 64);
    if (lane == 0) {
        float4* o = (float4*)(uv + (size_t)n * 8);
        o[0] = make_float4(pr[0], pr[1], pr[2], pr[3]);
        o[1] = make_float4(pr[4], pr[5], pr[6], pr[7]);
    }
}

__global__ __launch_bounds__(256) void k_classify(const int* __restrict__ ei, const float* __restrict__ uv,
                                                  const float* __restrict__ bc, float* __restrict__ out, int E) {
    int e = blockIdx.x * 256 + threadIdx.x;
    if (e >= E) return;
    int r = ei[e];
    int c = ei[E + e];
    float4 u = *(const float4*)(uv + (size_t)r * 8);
    float4 v = *(const float4*)(uv + (size_t)c * 8 + 4);
    float4 o;
    o.x = u.x + v.x + bc[0];
    o.y = u.y + v.y + bc[1];
    o.z = u.z + v.z + bc[2];
    o.w = u.w + v.w + bc[3];
    *(float4*)(out + (size_t)e * 4) = o;
}

// ---------------------------------------------------------------------------

extern "C" void kernel_launch(void* const* d_in, const int* in_sizes, int n_in,
                              void* d_out, int out_size, void* d_ws, size_t ws_size,
                              hipStream_t stream) {
    const float* x    = (const float*)d_in[0];
    const int*   ei   = (const int*)d_in[1];
    // d_in[2] = w (edge weights) ignored by reference
    const float* W1   = (const float*)d_in[3];
    const float* atS1 = (const float*)d_in[4];
    const float* atD1 = (const float*)d_in[5];
    const float* b1   = (const float*)d_in[6];
    const float* W2   = (const float*)d_in[7];
    const float* atS2 = (const float*)d_in[8];
    const float* atD2 = (const float*)d_in[9];
    const float* b2   = (const float*)d_in[10];
    const float* Wc   = (const float*)d_in[11];
    const float* bc   = (const float*)d_in[12];
    float* out = (float*)d_out;

    const int N = in_sizes[0] / 256;
    const int E = in_sizes[1] / 2;
    const int Etot = E + N;

    char* w = (char*)d_ws;
    size_t off = 0;
    auto alloc = [&](size_t b) { size_t o = off; off = (o + b + 255) & ~(size_t)255; return o; };
    // region A: xh|xl bf16 (51.2MB), later reused as h1h|h1l
    size_t oXH = alloc((size_t)N * 256 * 2);
    size_t oXL = alloc((size_t)N * 256 * 2);
    // region B: xp fp32 (51.2MB), later reused as xp2|h2|uv
    size_t oXP = alloc((size_t)N * 256 * 4);
    size_t oAS1 = alloc((size_t)N * 4 * 4);
    size_t oAD1 = alloc((size_t)N * 4 * 4);
    size_t oAS2 = alloc((size_t)N * 4);
    size_t oAD2 = alloc((size_t)N * 4);
    size_t oDEG = alloc((size_t)N * 4);
    size_t oCUR = alloc((size_t)N * 4);
    size_t oRP  = alloc((size_t)(N + 1) * 4);
    size_t oCSR = alloc((size_t)Etot * 4);
    size_t oW1H = alloc((size_t)256 * 256 * 2);
    size_t oW1L = alloc((size_t)256 * 256 * 2);
    size_t oW2H = alloc((size_t)256 * 64 * 2);
    size_t oW2L = alloc((size_t)256 * 64 * 2);
    (void)ws_size;

    unsigned short* xh  = (unsigned short*)(w + oXH);
    unsigned short* xl  = (unsigned short*)(w + oXL);
    unsigned short* h1h = (unsigned short*)(w + oXH);  // alias: xh dead after gemm1
    unsigned short* h1l = (unsigned short*)(w + oXL);
    float* xp  = (float*)(w + oXP);
    float* xp2 = (float*)(w + oXP);                    // alias: xp dead after agg1
    float* h2  = (float*)(w + oXP + (size_t)N * 64 * 4);
    float* uv  = (float*)(w + oXP + (size_t)N * 128 * 4);
    float* as1 = (float*)(w + oAS1);
    float* ad1 = (float*)(w + oAD1);
    float* as2 = (float*)(w + oAS2);
    float* ad2 = (float*)(w + oAD2);
    int* deg    = (int*)(w + oDEG);
    int* cur    = (int*)(w + oCUR);
    int* rowptr = (int*)(w + oRP);
    int* csr    = (int*)(w + oCSR);
    unsigned short* W1hT = (unsigned short*)(w + oW1H);
    unsigned short* W1lT = (unsigned short*)(w + oW1L);
    unsigned short* W2hT = (unsigned short*)(w + oW2H);
    unsigned short* W2lT = (unsigned short*)(w + oW2L);

    // CSR build
    k_init<<<(N + 255) / 256, 256, 0, stream>>>(deg, cur, N);
    k_hist<<<(E + 255) / 256, 256, 0, stream>>>(ei, deg, E);
    k_scan<<<1, 1024, 0, stream>>>(deg, rowptr, N);
    k_scatter<<<(Etot + 255) / 256, 256, 0, stream>>>(ei, rowptr, cur, csr, E, N);

    // packing
    k_pack_split<<<2048, 256, 0, stream>>>(x, xh, xl, (long)N * 64);
    k_pack_wT<<<(256 * 256 + 255) / 256, 256, 0, stream>>>(W1, W1hT, W1lT, 256, 256);
    k_pack_wT<<<(256 * 64 + 255) / 256, 256, 0, stream>>>(W2, W2hT, W2lT, 256, 64);

    // Layer 1
    dim3 g1((N + 63) / 64, 4);
    k_mfma_gemm<<<g1, 256, 0, stream>>>(xh, xl, W1hT, W1lT, xp, N, 256, 256);
    k_attn1<<<(N * 4 + 255) / 256, 256, 0, stream>>>(xp, atS1, atD1, as1, ad1, N);
    k_agg1<<<N, 256, 0, stream>>>(xp, as1, ad1, rowptr, csr, b1, h1h, h1l, N);

    // Layer 2
    dim3 g2((N + 63) / 64, 1);
    k_mfma_gemm<<<g2, 256, 0, stream>>>(h1h, h1l, W2hT, W2lT, xp2, N, 64, 256);
    k_attn2<<<(N + 255) / 256, 256, 0, stream>>>(xp2, atS2, atD2, as2, ad2, N);
    k_agg2<<<(N + 3) / 4, 256, 0, stream>>>(xp2, as2, ad2, rowptr, csr, b2, Wc, h2, uv, N);

    // Edge classifier
    k_classify<<<(E + 255) / 256, 256, 0, stream>>>(ei, uv, bc, out, E);
}

// Round 3
// 648.779 us; speedup vs baseline: 1.5152x; 1.2139x over previous
//
#include <hip/hip_runtime.h>

// ---------------------------------------------------------------------------
// GAT edge classifier, MI355X.
//   CSR build (deg hist -> scan -> scatter, with csr_dst)   [int atomics only]
//   pack: x -> (xh, xl) bf16 split; W1,W2 -> transposed bf16 splits
//   GEMM1 xp = x @ W1 via MFMA 16x16x32 bf16, 3-term split -> bf16 xpb
//   attn1 node dots (bf16 reads)
//   prep1: edge-parallel p[pos,h] = exp(leaky(as[s]+ad[d]))  (no max needed)
//   gather1: per-dst  h1 = (sum p*xpb)/(sum p) + b1, relu -> bf16 split
//   GEMM2 -> bf16 xp2b; attn2; prep2; gather2 (+fused uv = h2 @ Wc halves)
//   classify: out[e] = u[row] + v[col] + bc
// ---------------------------------------------------------------------------

#define NEG 0.2f

typedef __attribute__((ext_vector_type(8))) short bf16x8;
typedef __attribute__((ext_vector_type(4))) float f32x4;

__device__ __forceinline__ unsigned short f2bf(float f) {
    unsigned int u = __float_as_uint(f);
    unsigned int r = (u + 0x7FFFu + ((u >> 16) & 1u)) >> 16;   // RNE
    return (unsigned short)r;
}
__device__ __forceinline__ float bf2f(unsigned short h) {
    return __uint_as_float(((unsigned int)h) << 16);
}
__device__ __forceinline__ float lrelu(float x) { return x > 0.f ? x : NEG * x; }

// ------------------------------- CSR build --------------------------------

__global__ __launch_bounds__(256) void k_init(int* deg, int* cur, int n) {
    int i = blockIdx.x * 256 + threadIdx.x;
    if (i < n) { deg[i] = 1; cur[i] = 0; }  // deg starts at 1 for self-loop
}

__global__ __launch_bounds__(256) void k_hist(const int* __restrict__ ei, int* deg, int E) {
    int e = blockIdx.x * 256 + threadIdx.x;
    if (e < E) atomicAdd(&deg[ei[E + e]], 1);   // dst = ei[1][e]
}

__global__ __launch_bounds__(1024) void k_scan(const int* __restrict__ deg, int* __restrict__ rowptr, int n) {
    __shared__ int sums[1024];
    int t = threadIdx.x;
    int chunk = (n + 1023) >> 10;
    int lo = t * chunk, hi = min(lo + chunk, n);
    int s = 0;
    for (int i = lo; i < hi; i++) s += deg[i];
    sums[t] = s;
    __syncthreads();
    for (int off = 1; off < 1024; off <<= 1) {
        int v = (t >= off) ? sums[t - off] : 0;
        __syncthreads();
        sums[t] += v;
        __syncthreads();
    }
    int run = sums[t] - s;  // exclusive prefix at lo
    for (int i = lo; i < hi; i++) { rowptr[i] = run; run += deg[i]; }
    if (t == 1023) rowptr[n] = sums[1023];
}

__global__ __launch_bounds__(256) void k_scatter(const int* __restrict__ ei, const int* __restrict__ rowptr,
                                                 int* cur, int* csr_src, int* csr_dst, int E, int N) {
    int e = blockIdx.x * 256 + threadIdx.x;
    if (e < E) {
        int d = ei[E + e];
        int pos = rowptr[d] + atomicAdd(&cur[d], 1);
        csr_src[pos] = ei[e];
        csr_dst[pos] = d;
    } else if (e < E + N) {
        int i = e - E;  // self loop
        int pos = rowptr[i] + atomicAdd(&cur[i], 1);
        csr_src[pos] = i;
        csr_dst[pos] = i;
    }
}

// ------------------------------- packing ----------------------------------

__global__ __launch_bounds__(256) void k_pack_split(const float* __restrict__ src,
                                                    unsigned short* __restrict__ hi,
                                                    unsigned short* __restrict__ lo, long n4) {
    long i = (long)blockIdx.x * 256 + threadIdx.x;
    long stride = (long)gridDim.x * 256;
    for (; i < n4; i += stride) {
        float4 v = ((const float4*)src)[i];
        unsigned short h0 = f2bf(v.x), h1 = f2bf(v.y), h2 = f2bf(v.z), h3 = f2bf(v.w);
        ushort4 H = make_ushort4(h0, h1, h2, h3);
        ushort4 L = make_ushort4(f2bf(v.x - bf2f(h0)), f2bf(v.y - bf2f(h1)),
                                 f2bf(v.z - bf2f(h2)), f2bf(v.w - bf2f(h3)));
        ((ushort4*)hi)[i] = H;
        ((ushort4*)lo)[i] = L;
    }
}

// W [K,N] fp32 -> WT hi/lo bf16 [N,K]
__global__ __launch_bounds__(256) void k_pack_wT(const float* __restrict__ W,
                                                 unsigned short* __restrict__ hiT,
                                                 unsigned short* __restrict__ loT, int K, int N) {
    int t = blockIdx.x * 256 + threadIdx.x;
    if (t >= K * N) return;
    int n = t / K, k = t - n * K;
    float v = W[(size_t)k * N + n];
    unsigned short h = f2bf(v);
    hiT[t] = h;
    loT[t] = f2bf(v - bf2f(h));
}

// ------------------------------- MFMA GEMM --------------------------------
// C[M,N] = A[M,K] @ B[K,N]; A hi/lo bf16 row-major, B hi/lo bf16 [N,K].
// Output written as bf16 (RNE). Block 256 thr = 4 waves, tile 64x64.
__global__ __launch_bounds__(256) void k_mfma_gemm(const unsigned short* __restrict__ Ah,
                                                   const unsigned short* __restrict__ Al,
                                                   const unsigned short* __restrict__ BhT,
                                                   const unsigned short* __restrict__ BlT,
                                                   unsigned short* __restrict__ Cb, int M, int N, int K) {
    int wv = threadIdx.x >> 6, l = threadIdx.x & 63;
    int r = l & 15, hk = l >> 4;
    int m0 = blockIdx.x * 64 + wv * 16;
    int n0 = blockIdx.y * 64;
    int arow = min(m0 + r, M - 1);
    const unsigned short* aph = Ah + (size_t)arow * K + hk * 8;
    const unsigned short* apl = Al + (size_t)arow * K + hk * 8;
    const unsigned short* bbase = BhT + (size_t)(n0 + r) * K + hk * 8;
    const unsigned short* bbasel = BlT + (size_t)(n0 + r) * K + hk * 8;

    f32x4 acc[4] = {f32x4{0,0,0,0}, f32x4{0,0,0,0}, f32x4{0,0,0,0}, f32x4{0,0,0,0}};

#pragma unroll 2
    for (int k0 = 0; k0 < K; k0 += 32) {
        bf16x8 ah = *(const bf16x8*)(aph + k0);
        bf16x8 al = *(const bf16x8*)(apl + k0);
#pragma unroll
        for (int nf = 0; nf < 4; nf++) {
            bf16x8 bh = *(const bf16x8*)(bbase + (size_t)nf * 16 * K + k0);
            bf16x8 bl = *(const bf16x8*)(bbasel + (size_t)nf * 16 * K + k0);
            acc[nf] = __builtin_amdgcn_mfma_f32_16x16x32_bf16(ah, bh, acc[nf], 0, 0, 0);
            acc[nf] = __builtin_amdgcn_mfma_f32_16x16x32_bf16(ah, bl, acc[nf], 0, 0, 0);
            acc[nf] = __builtin_amdgcn_mfma_f32_16x16x32_bf16(al, bh, acc[nf], 0, 0, 0);
        }
    }
#pragma unroll
    for (int nf = 0; nf < 4; nf++) {
#pragma unroll
        for (int j = 0; j < 4; j++) {
            int m = m0 + hk * 4 + j;
            if (m < M) Cb[(size_t)m * N + n0 + nf * 16 + r] = f2bf(acc[nf][j]);
        }
    }
}

// ------------------------------- attention --------------------------------

// a_src/a_dst[n,h] from bf16 xpb; H heads of C=64 channels, thread=(n,h)
__global__ __launch_bounds__(256) void k_attn(const unsigned short* __restrict__ xpb,
                                              const float* __restrict__ att_s,
                                              const float* __restrict__ att_d,
                                              float* __restrict__ as, float* __restrict__ ad,
                                              int M, int H) {
    int idx = blockIdx.x * 256 + threadIdx.x;
    if (idx >= M * H) return;
    int n = idx / H, h = idx - n * H;
    const uint4* row = (const uint4*)(xpb + (size_t)n * (64 * H) + h * 64);
    const float* fs = att_s + h * 64;
    const float* fd = att_d + h * 64;
    float s = 0.f, d = 0.f;
#pragma unroll
    for (int j = 0; j < 8; j++) {
        uint4 v = row[j];
        unsigned int uu[4] = {v.x, v.y, v.z, v.w};
#pragma unroll
        for (int q = 0; q < 4; q++) {
            float lo = __uint_as_float(uu[q] << 16);
            float hi = __uint_as_float(uu[q] & 0xFFFF0000u);
            int c = j * 8 + q * 2;
            s += lo * fs[c] + hi * fs[c + 1];
            d += lo * fd[c] + hi * fd[c + 1];
        }
    }
    as[idx] = s; ad[idx] = d;
}

// edge-parallel softmax numerators (no max-sub: raw is O(3), exp safe in fp32)
__global__ __launch_bounds__(256) void k_prep1(const int* __restrict__ csr_src, const int* __restrict__ csr_dst,
                                               const float* __restrict__ as, const float* __restrict__ ad,
                                               float4* __restrict__ p, int Etot) {
    int pos = blockIdx.x * 256 + threadIdx.x;
    if (pos >= Etot) return;
    int s = csr_src[pos], d = csr_dst[pos];
    float4 a = ((const float4*)as)[s];
    float4 b = ((const float4*)ad)[d];
    float4 o;
    o.x = __expf(lrelu(a.x + b.x));
    o.y = __expf(lrelu(a.y + b.y));
    o.z = __expf(lrelu(a.z + b.z));
    o.w = __expf(lrelu(a.w + b.w));
    p[pos] = o;
}

__global__ __launch_bounds__(256) void k_prep2(const int* __restrict__ csr_src, const int* __restrict__ csr_dst,
                                               const float* __restrict__ as, const float* __restrict__ ad,
                                               float* __restrict__ p, int Etot) {
    int pos = blockIdx.x * 256 + threadIdx.x;
    if (pos >= Etot) return;
    p[pos] = __expf(lrelu(as[csr_src[pos]] + ad[csr_dst[pos]]));
}

// per-dst gather, layer 1: block=node, thread=col (256), h=t>>6
__global__ __launch_bounds__(256) void k_gather1(const unsigned short* __restrict__ xpb,
                                                 const float* __restrict__ p,
                                                 const int* __restrict__ rowptr, const int* __restrict__ csr_src,
                                                 const float* __restrict__ b1,
                                                 unsigned short* __restrict__ h1h, unsigned short* __restrict__ h1l,
                                                 int M) {
    int n = blockIdx.x;
    int t = threadIdx.x;
    int h = t >> 6;
    int start = rowptr[n], end = rowptr[n + 1];
    float den = 0.f, acc = 0.f;
    int s_nx = csr_src[start];
    float p_nx = p[start * 4 + h];
    for (int e = start; e < end; e++) {
        int s = s_nx; float pw = p_nx;
        if (e + 1 < end) { s_nx = csr_src[e + 1]; p_nx = p[(e + 1) * 4 + h]; }
        den += pw;
        acc += pw * bf2f(xpb[(size_t)s * 256 + t]);
    }
    float o = fmaxf(acc / (den + 1e-16f) + b1[t], 0.f);
    unsigned short hh = f2bf(o);
    h1h[(size_t)n * 256 + t] = hh;
    h1l[(size_t)n * 256 + t] = f2bf(o - bf2f(hh));
}

// per-dst gather, layer 2 (1 head, C=64): wave per node, fused uv = val . Wc
__global__ __launch_bounds__(256) void k_gather2(const unsigned short* __restrict__ xp2b,
                                                 const float* __restrict__ p,
                                                 const int* __restrict__ rowptr, const int* __restrict__ csr_src,
                                                 const float* __restrict__ b2, const float* __restrict__ Wc,
                                                 float* __restrict__ uv, int M) {
    int wave = threadIdx.x >> 6, lane = threadIdx.x & 63;
    int n = blockIdx.x * 4 + wave;
    if (n >= M) return;
    int start = rowptr[n], end = rowptr[n + 1];
    float den = 0.f, acc = 0.f;
    int s_nx = csr_src[start];
    float p_nx = p[start];
    for (int e = start; e < end; e++) {
        int s = s_nx; float pw = p_nx;
        if (e + 1 < end) { s_nx = csr_src[e + 1]; p_nx = p[e + 1]; }
        den += pw;
        acc += pw * bf2f(xp2b[(size_t)s * 64 + lane]);
    }
    float val = acc / (den + 1e-16f) + b2[lane];
    float pr[8];
#pragma unroll
    for (int j = 0; j < 4; j++) {
        pr[j]     = val * Wc[lane * 4 + j];
        pr[4 + j] = val * Wc[(64 + lane) * 4 + j];
    }
#pragma unroll
    for (int off = 32; off; off >>= 1)
#pragma unroll
        for (int j = 0; j < 8; j++) pr[j] += __shfl_xor(pr[j], off, 64);
    if (lane == 0) {
        float4* o = (float4*)(uv + (size_t)n * 8);
        o[0] = make_float4(pr[0], pr[1], pr[2], pr[3]);
        o[1] = make_float4(pr[4], pr[5], pr[6], pr[7]);
    }
}

__global__ __launch_bounds__(256) void k_classify(const int* __restrict__ ei, const float* __restrict__ uv,
                                                  const float* __restrict__ bc, float* __restrict__ out, int E) {
    int e = blockIdx.x * 256 + threadIdx.x;
    if (e >= E) return;
    int r = ei[e];
    int c = ei[E + e];
    float4 u = *(const float4*)(uv + (size_t)r * 8);
    float4 v = *(const float4*)(uv + (size_t)c * 8 + 4);
    float4 o;
    o.x = u.x + v.x + bc[0];
    o.y = u.y + v.y + bc[1];
    o.z = u.z + v.z + bc[2];
    o.w = u.w + v.w + bc[3];
    *(float4*)(out + (size_t)e * 4) = o;
}

// ---------------------------------------------------------------------------

extern "C" void kernel_launch(void* const* d_in, const int* in_sizes, int n_in,
                              void* d_out, int out_size, void* d_ws, size_t ws_size,
                              hipStream_t stream) {
    const float* x    = (const float*)d_in[0];
    const int*   ei   = (const int*)d_in[1];
    // d_in[2] = w (edge weights) ignored by reference
    const float* W1   = (const float*)d_in[3];
    const float* atS1 = (const float*)d_in[4];
    const float* atD1 = (const float*)d_in[5];
    const float* b1   = (const float*)d_in[6];
    const float* W2   = (const float*)d_in[7];
    const float* atS2 = (const float*)d_in[8];
    const float* atD2 = (const float*)d_in[9];
    const float* b2   = (const float*)d_in[10];
    const float* Wc   = (const float*)d_in[11];
    const float* bc   = (const float*)d_in[12];
    float* out = (float*)d_out;

    const int N = in_sizes[0] / 256;
    const int E = in_sizes[1] / 2;
    const int Etot = E + N;

    char* w = (char*)d_ws;
    size_t off = 0;
    auto alloc = [&](size_t b) { size_t o = off; off = (o + b + 255) & ~(size_t)255; return o; };
    size_t oXH  = alloc((size_t)N * 256 * 2);   // x hi split; later h1h
    size_t oXL  = alloc((size_t)N * 256 * 2);   // x lo split; later h1l
    size_t oXPB = alloc((size_t)N * 256 * 2);   // xp bf16; later xp2b|uv
    size_t oP1  = alloc((size_t)Etot * 4 * 4);  // p layer1; later p layer2
    size_t oAS1 = alloc((size_t)N * 4 * 4);
    size_t oAD1 = alloc((size_t)N * 4 * 4);
    size_t oDEG = alloc((size_t)N * 4);
    size_t oCUR = alloc((size_t)N * 4);
    size_t oRP  = alloc((size_t)(N + 1) * 4);
    size_t oCSR = alloc((size_t)Etot * 4);
    size_t oCSD = alloc((size_t)Etot * 4);
    size_t oW1H = alloc((size_t)256 * 256 * 2);
    size_t oW1L = alloc((size_t)256 * 256 * 2);
    size_t oW2H = alloc((size_t)256 * 64 * 2);
    size_t oW2L = alloc((size_t)256 * 64 * 2);
    (void)ws_size;

    unsigned short* xh   = (unsigned short*)(w + oXH);
    unsigned short* xl   = (unsigned short*)(w + oXL);
    unsigned short* h1h  = (unsigned short*)(w + oXH);   // alias: xh dead after gemm1
    unsigned short* h1l  = (unsigned short*)(w + oXL);
    unsigned short* xpb  = (unsigned short*)(w + oXPB);
    unsigned short* xp2b = (unsigned short*)(w + oXPB);  // alias: xpb dead after gather1
    float* uv  = (float*)(w + oXPB + (size_t)N * 64 * 2 + 256);  // past xp2b, aligned
    uv = (float*)(((uintptr_t)uv + 255) & ~(uintptr_t)255);
    float* p1  = (float*)(w + oP1);
    float* p2  = (float*)(w + oP1);                      // alias: p1 dead after gather1
    float* as1 = (float*)(w + oAS1);
    float* ad1 = (float*)(w + oAD1);
    float* as2 = (float*)(w + oAS1);                     // alias: as1 dead after prep1
    float* ad2 = (float*)(w + oAD1);
    int* deg    = (int*)(w + oDEG);
    int* cur    = (int*)(w + oCUR);
    int* rowptr = (int*)(w + oRP);
    int* csr    = (int*)(w + oCSR);
    int* csrd   = (int*)(w + oCSD);
    unsigned short* W1hT = (unsigned short*)(w + oW1H);
    unsigned short* W1lT = (unsigned short*)(w + oW1L);
    unsigned short* W2hT = (unsigned short*)(w + oW2H);
    unsigned short* W2lT = (unsigned short*)(w + oW2L);

    // CSR build
    k_init<<<(N + 255) / 256, 256, 0, stream>>>(deg, cur, N);
    k_hist<<<(E + 255) / 256, 256, 0, stream>>>(ei, deg, E);
    k_scan<<<1, 1024, 0, stream>>>(deg, rowptr, N);
    k_scatter<<<(Etot + 255) / 256, 256, 0, stream>>>(ei, rowptr, cur, csr, csrd, E, N);

    // packing
    k_pack_split<<<2048, 256, 0, stream>>>(x, xh, xl, (long)N * 64);
    k_pack_wT<<<(256 * 256 + 255) / 256, 256, 0, stream>>>(W1, W1hT, W1lT, 256, 256);
    k_pack_wT<<<(256 * 64 + 255) / 256, 256, 0, stream>>>(W2, W2hT, W2lT, 256, 64);

    // Layer 1
    dim3 g1((N + 63) / 64, 4);
    k_mfma_gemm<<<g1, 256, 0, stream>>>(xh, xl, W1hT, W1lT, xpb, N, 256, 256);
    k_attn<<<(N * 4 + 255) / 256, 256, 0, stream>>>(xpb, atS1, atD1, as1, ad1, N, 4);
    k_prep1<<<(Etot + 255) / 256, 256, 0, stream>>>(csr, csrd, as1, ad1, (float4*)p1, Etot);
    k_gather1<<<N, 256, 0, stream>>>(xpb, p1, rowptr, csr, b1, h1h, h1l, N);

    // Layer 2
    dim3 g2((N + 63) / 64, 1);
    k_mfma_gemm<<<g2, 256, 0, stream>>>(h1h, h1l, W2hT, W2lT, xp2b, N, 64, 256);
    k_attn<<<(N + 255) / 256, 256, 0, stream>>>(xp2b, atS2, atD2, as2, ad2, N, 1);
    k_prep2<<<(Etot + 255) / 256, 256, 0, stream>>>(csr, csrd, as2, ad2, p2, Etot);
    k_gather2<<<(N + 3) / 4, 256, 0, stream>>>(xp2b, p2, rowptr, csr, b2, Wc, uv, N);

    // Edge classifier
    k_classify<<<(E + 255) / 256, 256, 0, stream>>>(ei, uv, bc, out, E);
}

// Round 4
// 500.215 us; speedup vs baseline: 1.9652x; 1.2970x over previous
//
#include <hip/hip_runtime.h>

// ---------------------------------------------------------------------------
// GAT edge classifier, MI355X.
//   CSR build (deg hist -> scan -> scatter, with csr_dst)   [int atomics only]
//   pack: x -> (xh, xl) bf16 split; W1,W2 -> transposed bf16 splits
//   GEMM1 xp = x @ W1 via MFMA 16x16x32 bf16, 3-term split -> bf16 xpb
//   attn1 node dots (bf16 reads)
//   gather1: per-dst, 1 wave/node, 8B/lane row loads, fused p=exp(lrelu(.)),
//            2-edge ILP -> h1 bf16 split (relu+bias)
//   GEMM2 -> bf16 xp2b; attn2; gather2 (4-edge/wave groups, fused uv=h2@Wc)
//   classify: out[e] = u[row] + v[col] + bc
// ---------------------------------------------------------------------------

#define NEG 0.2f

typedef __attribute__((ext_vector_type(8))) short bf16x8;
typedef __attribute__((ext_vector_type(4))) float f32x4;

__device__ __forceinline__ unsigned short f2bf(float f) {
    unsigned int u = __float_as_uint(f);
    unsigned int r = (u + 0x7FFFu + ((u >> 16) & 1u)) >> 16;   // RNE
    return (unsigned short)r;
}
__device__ __forceinline__ float bf2f(unsigned short h) {
    return __uint_as_float(((unsigned int)h) << 16);
}
__device__ __forceinline__ float bflo(unsigned int u) { return __uint_as_float(u << 16); }
__device__ __forceinline__ float bfhi(unsigned int u) { return __uint_as_float(u & 0xFFFF0000u); }
__device__ __forceinline__ float lrelu(float x) { return x > 0.f ? x : NEG * x; }

// ------------------------------- CSR build --------------------------------

__global__ __launch_bounds__(256) void k_init(int* deg, int* cur, int n) {
    int i = blockIdx.x * 256 + threadIdx.x;
    if (i < n) { deg[i] = 1; cur[i] = 0; }  // deg starts at 1 for self-loop
}

__global__ __launch_bounds__(256) void k_hist(const int* __restrict__ ei, int* deg, int E) {
    int e = blockIdx.x * 256 + threadIdx.x;
    if (e < E) atomicAdd(&deg[ei[E + e]], 1);   // dst = ei[1][e]
}

__global__ __launch_bounds__(1024) void k_scan(const int* __restrict__ deg, int* __restrict__ rowptr, int n) {
    __shared__ int sums[1024];
    int t = threadIdx.x;
    int chunk = (n + 1023) >> 10;
    int lo = t * chunk, hi = min(lo + chunk, n);
    int s = 0;
    for (int i = lo; i < hi; i++) s += deg[i];
    sums[t] = s;
    __syncthreads();
    for (int off = 1; off < 1024; off <<= 1) {
        int v = (t >= off) ? sums[t - off] : 0;
        __syncthreads();
        sums[t] += v;
        __syncthreads();
    }
    int run = sums[t] - s;  // exclusive prefix at lo
    for (int i = lo; i < hi; i++) { rowptr[i] = run; run += deg[i]; }
    if (t == 1023) rowptr[n] = sums[1023];
}

__global__ __launch_bounds__(256) void k_scatter(const int* __restrict__ ei, const int* __restrict__ rowptr,
                                                 int* cur, int* csr_src, int E, int N) {
    int e = blockIdx.x * 256 + threadIdx.x;
    if (e < E) {
        int d = ei[E + e];
        int pos = rowptr[d] + atomicAdd(&cur[d], 1);
        csr_src[pos] = ei[e];
    } else if (e < E + N) {
        int i = e - E;  // self loop
        int pos = rowptr[i] + atomicAdd(&cur[i], 1);
        csr_src[pos] = i;
    }
}

// ------------------------------- packing ----------------------------------

__global__ __launch_bounds__(256) void k_pack_split(const float* __restrict__ src,
                                                    unsigned short* __restrict__ hi,
                                                    unsigned short* __restrict__ lo, long n4) {
    long i = (long)blockIdx.x * 256 + threadIdx.x;
    long stride = (long)gridDim.x * 256;
    for (; i < n4; i += stride) {
        float4 v = ((const float4*)src)[i];
        unsigned short h0 = f2bf(v.x), h1 = f2bf(v.y), h2 = f2bf(v.z), h3 = f2bf(v.w);
        ushort4 H = make_ushort4(h0, h1, h2, h3);
        ushort4 L = make_ushort4(f2bf(v.x - bf2f(h0)), f2bf(v.y - bf2f(h1)),
                                 f2bf(v.z - bf2f(h2)), f2bf(v.w - bf2f(h3)));
        ((ushort4*)hi)[i] = H;
        ((ushort4*)lo)[i] = L;
    }
}

// W [K,N] fp32 -> WT hi/lo bf16 [N,K]
__global__ __launch_bounds__(256) void k_pack_wT(const float* __restrict__ W,
                                                 unsigned short* __restrict__ hiT,
                                                 unsigned short* __restrict__ loT, int K, int N) {
    int t = blockIdx.x * 256 + threadIdx.x;
    if (t >= K * N) return;
    int n = t / K, k = t - n * K;
    float v = W[(size_t)k * N + n];
    unsigned short h = f2bf(v);
    hiT[t] = h;
    loT[t] = f2bf(v - bf2f(h));
}

// ------------------------------- MFMA GEMM --------------------------------
// C[M,N] = A[M,K] @ B[K,N]; A hi/lo bf16 row-major, B hi/lo bf16 [N,K].
// Output written as bf16 (RNE). Block 256 thr = 4 waves, tile 64x64.
__global__ __launch_bounds__(256) void k_mfma_gemm(const unsigned short* __restrict__ Ah,
                                                   const unsigned short* __restrict__ Al,
                                                   const unsigned short* __restrict__ BhT,
                                                   const unsigned short* __restrict__ BlT,
                                                   unsigned short* __restrict__ Cb, int M, int N, int K) {
    int wv = threadIdx.x >> 6, l = threadIdx.x & 63;
    int r = l & 15, hk = l >> 4;
    int m0 = blockIdx.x * 64 + wv * 16;
    int n0 = blockIdx.y * 64;
    int arow = min(m0 + r, M - 1);
    const unsigned short* aph = Ah + (size_t)arow * K + hk * 8;
    const unsigned short* apl = Al + (size_t)arow * K + hk * 8;
    const unsigned short* bbase = BhT + (size_t)(n0 + r) * K + hk * 8;
    const unsigned short* bbasel = BlT + (size_t)(n0 + r) * K + hk * 8;

    f32x4 acc[4] = {f32x4{0,0,0,0}, f32x4{0,0,0,0}, f32x4{0,0,0,0}, f32x4{0,0,0,0}};

#pragma unroll 2
    for (int k0 = 0; k0 < K; k0 += 32) {
        bf16x8 ah = *(const bf16x8*)(aph + k0);
        bf16x8 al = *(const bf16x8*)(apl + k0);
#pragma unroll
        for (int nf = 0; nf < 4; nf++) {
            bf16x8 bh = *(const bf16x8*)(bbase + (size_t)nf * 16 * K + k0);
            bf16x8 bl = *(const bf16x8*)(bbasel + (size_t)nf * 16 * K + k0);
            acc[nf] = __builtin_amdgcn_mfma_f32_16x16x32_bf16(ah, bh, acc[nf], 0, 0, 0);
            acc[nf] = __builtin_amdgcn_mfma_f32_16x16x32_bf16(ah, bl, acc[nf], 0, 0, 0);
            acc[nf] = __builtin_amdgcn_mfma_f32_16x16x32_bf16(al, bh, acc[nf], 0, 0, 0);
        }
    }
#pragma unroll
    for (int nf = 0; nf < 4; nf++) {
#pragma unroll
        for (int j = 0; j < 4; j++) {
            int m = m0 + hk * 4 + j;
            if (m < M) Cb[(size_t)m * N + n0 + nf * 16 + r] = f2bf(acc[nf][j]);
        }
    }
}

// ------------------------------- attention --------------------------------

// a_src/a_dst[n,h] from bf16 xpb; H heads of C=64 channels, thread=(n,h)
__global__ __launch_bounds__(256) void k_attn(const unsigned short* __restrict__ xpb,
                                              const float* __restrict__ att_s,
                                              const float* __restrict__ att_d,
                                              float* __restrict__ as, float* __restrict__ ad,
                                              int M, int H) {
    int idx = blockIdx.x * 256 + threadIdx.x;
    if (idx >= M * H) return;
    int n = idx / H, h = idx - n * H;
    const uint4* row = (const uint4*)(xpb + (size_t)n * (64 * H) + h * 64);
    const float* fs = att_s + h * 64;
    const float* fd = att_d + h * 64;
    float s = 0.f, d = 0.f;
#pragma unroll
    for (int j = 0; j < 8; j++) {
        uint4 v = row[j];
        unsigned int uu[4] = {v.x, v.y, v.z, v.w};
#pragma unroll
        for (int q = 0; q < 4; q++) {
            float lo = bflo(uu[q]);
            float hi = bfhi(uu[q]);
            int c = j * 8 + q * 2;
            s += lo * fs[c] + hi * fs[c + 1];
            d += lo * fd[c] + hi * fd[c + 1];
        }
    }
    as[idx] = s; ad[idx] = d;
}

// gather layer 1: 1 wave/node, lane owns 4 cols (8B), head h=lane>>4.
// p computed inline from as/ad (no max-sub: raw is O(3), exp safe in fp32).
__global__ __launch_bounds__(256) void k_gather1(const unsigned short* __restrict__ xpb,
                                                 const float* __restrict__ as, const float* __restrict__ ad,
                                                 const int* __restrict__ rowptr, const int* __restrict__ csr_src,
                                                 const float* __restrict__ b1,
                                                 unsigned short* __restrict__ h1h, unsigned short* __restrict__ h1l,
                                                 int M) {
    int wv = threadIdx.x >> 6, lane = threadIdx.x & 63;
    int n = blockIdx.x * 4 + wv;
    if (n >= M) return;
    int h = lane >> 4;
    float adv = ad[n * 4 + h];
    int start = rowptr[n], end = rowptr[n + 1];
    float acc0[4] = {0.f, 0.f, 0.f, 0.f}, acc1[4] = {0.f, 0.f, 0.f, 0.f};
    float den0 = 0.f, den1 = 0.f;
    int e = start;
    for (; e + 1 < end; e += 2) {
        int s0 = csr_src[e], s1 = csr_src[e + 1];
        uint2 v0 = *(const uint2*)(xpb + (size_t)s0 * 256 + lane * 4);
        uint2 v1 = *(const uint2*)(xpb + (size_t)s1 * 256 + lane * 4);
        float p0 = __expf(lrelu(as[s0 * 4 + h] + adv));
        float p1 = __expf(lrelu(as[s1 * 4 + h] + adv));
        den0 += p0; den1 += p1;
        acc0[0] += p0 * bflo(v0.x); acc0[1] += p0 * bfhi(v0.x);
        acc0[2] += p0 * bflo(v0.y); acc0[3] += p0 * bfhi(v0.y);
        acc1[0] += p1 * bflo(v1.x); acc1[1] += p1 * bfhi(v1.x);
        acc1[2] += p1 * bflo(v1.y); acc1[3] += p1 * bfhi(v1.y);
    }
    if (e < end) {
        int s0 = csr_src[e];
        uint2 v0 = *(const uint2*)(xpb + (size_t)s0 * 256 + lane * 4);
        float p0 = __expf(lrelu(as[s0 * 4 + h] + adv));
        den0 += p0;
        acc0[0] += p0 * bflo(v0.x); acc0[1] += p0 * bfhi(v0.x);
        acc0[2] += p0 * bflo(v0.y); acc0[3] += p0 * bfhi(v0.y);
    }
    float dinv = 1.f / (den0 + den1 + 1e-16f);
    const float4 bb = *(const float4*)(b1 + lane * 4);
    float o0 = fmaxf((acc0[0] + acc1[0]) * dinv + bb.x, 0.f);
    float o1 = fmaxf((acc0[1] + acc1[1]) * dinv + bb.y, 0.f);
    float o2 = fmaxf((acc0[2] + acc1[2]) * dinv + bb.z, 0.f);
    float o3 = fmaxf((acc0[3] + acc1[3]) * dinv + bb.w, 0.f);
    unsigned short q0 = f2bf(o0), q1 = f2bf(o1), q2 = f2bf(o2), q3 = f2bf(o3);
    uint2 H, L;
    H.x = (unsigned)q0 | ((unsigned)q1 << 16);
    H.y = (unsigned)q2 | ((unsigned)q3 << 16);
    L.x = (unsigned)f2bf(o0 - bf2f(q0)) | ((unsigned)f2bf(o1 - bf2f(q1)) << 16);
    L.y = (unsigned)f2bf(o2 - bf2f(q2)) | ((unsigned)f2bf(o3 - bf2f(q3)) << 16);
    *(uint2*)(h1h + (size_t)n * 256 + lane * 4) = H;
    *(uint2*)(h1l + (size_t)n * 256 + lane * 4) = L;
}

// gather layer 2 (1 head, C=64): 1 wave/node, 4 edge-groups of 16 lanes,
// lane q=lane&15 owns 4 cols (8B). Fused uv = (h2+b2) . Wc halves.
__global__ __launch_bounds__(256) void k_gather2(const unsigned short* __restrict__ xp2b,
                                                 const float* __restrict__ as, const float* __restrict__ ad,
                                                 const int* __restrict__ rowptr, const int* __restrict__ csr_src,
                                                 const float* __restrict__ b2, const float* __restrict__ Wc,
                                                 float* __restrict__ uv, int M) {
    int wv = threadIdx.x >> 6, lane = threadIdx.x & 63;
    int n = blockIdx.x * 4 + wv;
    if (n >= M) return;
    int g = lane >> 4, q = lane & 15;
    float adv = ad[n];
    int start = rowptr[n], end = rowptr[n + 1];
    float acc[4] = {0.f, 0.f, 0.f, 0.f};
    float den = 0.f;
    for (int e = start; e < end; e += 4) {
        int ee = e + g;
        bool ok = ee < end;
        int s = csr_src[ok ? ee : start];
        uint2 v = *(const uint2*)(xp2b + (size_t)s * 64 + q * 4);
        float pw = ok ? __expf(lrelu(as[s] + adv)) : 0.f;
        den += pw;
        acc[0] += pw * bflo(v.x); acc[1] += pw * bfhi(v.x);
        acc[2] += pw * bflo(v.y); acc[3] += pw * bfhi(v.y);
    }
#pragma unroll
    for (int j = 0; j < 4; j++) {
        acc[j] += __shfl_xor(acc[j], 16, 64);
        acc[j] += __shfl_xor(acc[j], 32, 64);
    }
    den += __shfl_xor(den, 16, 64);
    den += __shfl_xor(den, 32, 64);
    float dinv = 1.f / (den + 1e-16f);
    float pr[8] = {0.f, 0.f, 0.f, 0.f, 0.f, 0.f, 0.f, 0.f};
#pragma unroll
    for (int j = 0; j < 4; j++) {
        int c = q * 4 + j;
        float val = acc[j] * dinv + b2[c];
#pragma unroll
        for (int k = 0; k < 4; k++) {
            pr[k]     += val * Wc[c * 4 + k];
            pr[4 + k] += val * Wc[(64 + c) * 4 + k];
        }
    }
#pragma unroll
    for (int off = 1; off <= 8; off <<= 1)
#pragma unroll
        for (int j = 0; j < 8; j++) pr[j] += __shfl_xor(pr[j], off, 64);
    if (lane == 0) {
        float4* o = (float4*)(uv + (size_t)n * 8);
        o[0] = make_float4(pr[0], pr[1], pr[2], pr[3]);
        o[1] = make_float4(pr[4], pr[5], pr[6], pr[7]);
    }
}

__global__ __launch_bounds__(256) void k_classify(const int* __restrict__ ei, const float* __restrict__ uv,
                                                  const float* __restrict__ bc, float* __restrict__ out, int E) {
    int e = blockIdx.x * 256 + threadIdx.x;
    if (e >= E) return;
    int r = ei[e];
    int c = ei[E + e];
    float4 u = *(const float4*)(uv + (size_t)r * 8);
    float4 v = *(const float4*)(uv + (size_t)c * 8 + 4);
    float4 o;
    o.x = u.x + v.x + bc[0];
    o.y = u.y + v.y + bc[1];
    o.z = u.z + v.z + bc[2];
    o.w = u.w + v.w + bc[3];
    *(float4*)(out + (size_t)e * 4) = o;
}

// ---------------------------------------------------------------------------

extern "C" void kernel_launch(void* const* d_in, const int* in_sizes, int n_in,
                              void* d_out, int out_size, void* d_ws, size_t ws_size,
                              hipStream_t stream) {
    const float* x    = (const float*)d_in[0];
    const int*   ei   = (const int*)d_in[1];
    // d_in[2] = w (edge weights) ignored by reference
    const float* W1   = (const float*)d_in[3];
    const float* atS1 = (const float*)d_in[4];
    const float* atD1 = (const float*)d_in[5];
    const float* b1   = (const float*)d_in[6];
    const float* W2   = (const float*)d_in[7];
    const float* atS2 = (const float*)d_in[8];
    const float* atD2 = (const float*)d_in[9];
    const float* b2   = (const float*)d_in[10];
    const float* Wc   = (const float*)d_in[11];
    const float* bc   = (const float*)d_in[12];
    float* out = (float*)d_out;

    const int N = in_sizes[0] / 256;
    const int E = in_sizes[1] / 2;
    const int Etot = E + N;

    char* w = (char*)d_ws;
    size_t off = 0;
    auto alloc = [&](size_t b) { size_t o = off; off = (o + b + 255) & ~(size_t)255; return o; };
    size_t oXH  = alloc((size_t)N * 256 * 2);   // x hi split; later h1h
    size_t oXL  = alloc((size_t)N * 256 * 2);   // x lo split; later h1l
    size_t oXPB = alloc((size_t)N * 256 * 2);   // xp bf16; later xp2b|uv
    size_t oAS1 = alloc((size_t)N * 4 * 4);
    size_t oAD1 = alloc((size_t)N * 4 * 4);
    size_t oDEG = alloc((size_t)N * 4);
    size_t oCUR = alloc((size_t)N * 4);
    size_t oRP  = alloc((size_t)(N + 1) * 4);
    size_t oCSR = alloc((size_t)Etot * 4);
    size_t oW1H = alloc((size_t)256 * 256 * 2);
    size_t oW1L = alloc((size_t)256 * 256 * 2);
    size_t oW2H = alloc((size_t)256 * 64 * 2);
    size_t oW2L = alloc((size_t)256 * 64 * 2);
    (void)ws_size;

    unsigned short* xh   = (unsigned short*)(w + oXH);
    unsigned short* xl   = (unsigned short*)(w + oXL);
    unsigned short* h1h  = (unsigned short*)(w + oXH);   // alias: xh dead after gemm1
    unsigned short* h1l  = (unsigned short*)(w + oXL);
    unsigned short* xpb  = (unsigned short*)(w + oXPB);
    unsigned short* xp2b = (unsigned short*)(w + oXPB);  // alias: xpb dead after gather1
    float* uv  = (float*)(w + oXPB + (size_t)N * 64 * 2 + 256);
    uv = (float*)(((uintptr_t)uv + 255) & ~(uintptr_t)255);
    float* as1 = (float*)(w + oAS1);
    float* ad1 = (float*)(w + oAD1);
    float* as2 = (float*)(w + oAS1);                     // alias: as1 dead after gather1
    float* ad2 = (float*)(w + oAD1);
    int* deg    = (int*)(w + oDEG);
    int* cur    = (int*)(w + oCUR);
    int* rowptr = (int*)(w + oRP);
    int* csr    = (int*)(w + oCSR);
    unsigned short* W1hT = (unsigned short*)(w + oW1H);
    unsigned short* W1lT = (unsigned short*)(w + oW1L);
    unsigned short* W2hT = (unsigned short*)(w + oW2H);
    unsigned short* W2lT = (unsigned short*)(w + oW2L);

    // CSR build
    k_init<<<(N + 255) / 256, 256, 0, stream>>>(deg, cur, N);
    k_hist<<<(E + 255) / 256, 256, 0, stream>>>(ei, deg, E);
    k_scan<<<1, 1024, 0, stream>>>(deg, rowptr, N);
    k_scatter<<<(Etot + 255) / 256, 256, 0, stream>>>(ei, rowptr, cur, csr, E, N);

    // packing
    k_pack_split<<<2048, 256, 0, stream>>>(x, xh, xl, (long)N * 64);
    k_pack_wT<<<(256 * 256 + 255) / 256, 256, 0, stream>>>(W1, W1hT, W1lT, 256, 256);
    k_pack_wT<<<(256 * 64 + 255) / 256, 256, 0, stream>>>(W2, W2hT, W2lT, 256, 64);

    // Layer 1
    dim3 g1((N + 63) / 64, 4);
    k_mfma_gemm<<<g1, 256, 0, stream>>>(xh, xl, W1hT, W1lT, xpb, N, 256, 256);
    k_attn<<<(N * 4 + 255) / 256, 256, 0, stream>>>(xpb, atS1, atD1, as1, ad1, N, 4);
    k_gather1<<<(N + 3) / 4, 256, 0, stream>>>(xpb, as1, ad1, rowptr, csr, b1, h1h, h1l, N);

    // Layer 2
    dim3 g2((N + 63) / 64, 1);
    k_mfma_gemm<<<g2, 256, 0, stream>>>(h1h, h1l, W2hT, W2lT, xp2b, N, 64, 256);
    k_attn<<<(N + 255) / 256, 256, 0, stream>>>(xp2b, atS2, atD2, as2, ad2, N, 1);
    k_gather2<<<(N + 3) / 4, 256, 0, stream>>>(xp2b, as2, ad2, rowptr, csr, b2, Wc, uv, N);

    // Edge classifier
    k_classify<<<(E + 255) / 256, 256, 0, stream>>>(ei, uv, bc, out, E);
}